// Round 1
// baseline (151.856 us; speedup 1.0000x reference)
//
#include <hip/hip_runtime.h>
#include <math.h>

#define SS 8
#define NN 4096
#define MM 64
#define LBOX 20.0f

// One wave (64 lanes) per atom; lane = neighbor slot. 4 atoms per 256-thread block.
// Factored algebra: P[16][4] = sum_m h2_m (x) rt_m ; q[4] = sum_m rt_m
//                  A[32][4] = en3_w^T P + en3_b (x) q ; D[32][16] = A * A[:16]^T
__global__ __launch_bounds__(256) void desc_kernel(
    const float* __restrict__ pos,      // [S*N*3]
    const int*   __restrict__ types,    // [S*N]
    const int*   __restrict__ neigh,    // [S*N*M]
    const float* __restrict__ es1_w, const float* __restrict__ es1_b,
    const float* __restrict__ es2_w, const float* __restrict__ es2_b,
    const float* __restrict__ fs1_w, const float* __restrict__ fs1_b,
    const float* __restrict__ fs2_w, const float* __restrict__ fs2_b,
    const float* __restrict__ en1_w, const float* __restrict__ en1_b,
    const float* __restrict__ en2_w, const float* __restrict__ en2_b,
    const float* __restrict__ en3_w, const float* __restrict__ en3_b,
    float* __restrict__ out)            // [S*N*32*16]
{
    __shared__ alignas(16) float sh_vt[32];      // [pair t][8] : td[t] @ en1_w
    __shared__ alignas(16) float sh_b1[8];
    __shared__ alignas(16) float sh_W2t[128];    // [k out][i in] transposed en2_w
    __shared__ alignas(16) float sh_b2[16];
    __shared__ alignas(16) float sh_W3[512];     // en3_w row-major [h][g]
    __shared__ alignas(16) float sh_b3[32];
    __shared__ alignas(16) float sh_h2[4][64*17];  // stride 17 pad
    __shared__ alignas(16) float sh_rt[4][64*5];   // stride 5 pad
    __shared__ alignas(16) float sh_P[4][64];
    __shared__ alignas(16) float sh_A[4][128];

    const int tid = threadIdx.x;

    // ---------------- per-block weight preprocessing ----------------
    if (tid < 4) {
        const float ti = (float)(tid >> 1), tj = (float)(tid & 1);
        float e[4] = {0.f, 0.f, 0.f, 0.f};
        #pragma unroll
        for (int swp = 0; swp < 2; ++swp) {
            const float a = swp ? tj : ti, b = swp ? ti : tj;
            float h[4];
            #pragma unroll
            for (int k = 0; k < 4; ++k)
                h[k] = fmaxf(a * es1_w[k] + b * es1_w[4 + k] + es1_b[k], 0.f);
            #pragma unroll
            for (int k = 0; k < 4; ++k) {
                float acc = es2_b[k];
                #pragma unroll
                for (int j = 0; j < 4; ++j) acc += h[j] * es2_w[j * 4 + k];
                e[k] += acc;
            }
        }
        float f[4];
        #pragma unroll
        for (int k = 0; k < 4; ++k) {
            float acc = fs1_b[k];
            #pragma unroll
            for (int j = 0; j < 4; ++j) acc += e[j] * fs1_w[j * 4 + k];
            f[k] = fmaxf(acc, 0.f);
        }
        float td[4];
        #pragma unroll
        for (int k = 0; k < 4; ++k) {
            float acc = fs2_b[k];
            #pragma unroll
            for (int j = 0; j < 4; ++j) acc += f[j] * fs2_w[j * 4 + k];
            td[k] = acc;
        }
        #pragma unroll
        for (int o = 0; o < 8; ++o) {
            float acc = 0.f;
            #pragma unroll
            for (int d = 0; d < 4; ++d) acc += td[d] * en1_w[d * 8 + o];
            sh_vt[tid * 8 + o] = acc;
        }
    }
    if (tid < 8)  sh_b1[tid] = en1_b[tid];
    if (tid < 16) sh_b2[tid] = en2_b[tid];
    if (tid < 32) sh_b3[tid] = en3_b[tid];
    if (tid < 128) { const int k = tid >> 3, i = tid & 7; sh_W2t[tid] = en2_w[i * 16 + k]; }
    sh_W3[tid]       = en3_w[tid];
    sh_W3[tid + 256] = en3_w[tid + 256];
    __syncthreads();

    const int wave = tid >> 6;
    const int lane = tid & 63;
    const int atom = blockIdx.x * 4 + wave;      // = s*N + n
    const int sbase = atom & ~(NN - 1);          // s*N

    float* __restrict__ h2w = sh_h2[wave];
    float* __restrict__ rtw = sh_rt[wave];

    // ---------------- per-neighbor geometry ----------------
    const float xi = pos[atom * 3 + 0];
    const float yi = pos[atom * 3 + 1];
    const float zi = pos[atom * 3 + 2];
    const int   ti = types[atom];

    const int nb  = neigh[atom * MM + lane];
    const int msk = nb < 0;
    const int j   = msk ? 0 : nb;
    const int gj  = sbase + j;

    float dx = pos[gj * 3 + 0] - xi;
    float dy = pos[gj * 3 + 1] - yi;
    float dz = pos[gj * 3 + 2] - zi;
    dx -= LBOX * rintf(dx * (1.0f / LBOX));
    dy -= LBOX * rintf(dy * (1.0f / LBOX));
    dz -= LBOX * rintf(dz * (1.0f / LBOX));
    const float r2   = fmaf(dx, dx, fmaf(dy, dy, fmaf(dz, dz, 1e-12f)));
    const float rinv = rsqrtf(r2);
    const float r    = r2 * rinv;
    const float u    = (r - 2.0f) * 0.25f;
    float swv = 0.5f * __cosf(3.14159265358979323846f * u) + 0.5f;
    swv = (r < 2.0f) ? 1.0f : ((r < 6.0f) ? swv : 0.0f);
    const float sij   = msk ? 0.0f : swv * rinv;
    const float scale = sij * rinv;
    const float rt0 = sij, rt1 = dx * scale, rt2 = dy * scale, rt3 = dz * scale;

    const int tj = types[gj];
    const int tt = ti * 2 + tj;

    // ---------------- layer 1 (folded): h1 = relu(sij*vt[tt] + b1) ----------------
    float h1[8];
    {
        const float4 va = *(const float4*)(sh_vt + tt * 8);
        const float4 vb = *(const float4*)(sh_vt + tt * 8 + 4);
        h1[0] = fmaxf(fmaf(sij, va.x, sh_b1[0]), 0.f);
        h1[1] = fmaxf(fmaf(sij, va.y, sh_b1[1]), 0.f);
        h1[2] = fmaxf(fmaf(sij, va.z, sh_b1[2]), 0.f);
        h1[3] = fmaxf(fmaf(sij, va.w, sh_b1[3]), 0.f);
        h1[4] = fmaxf(fmaf(sij, vb.x, sh_b1[4]), 0.f);
        h1[5] = fmaxf(fmaf(sij, vb.y, sh_b1[5]), 0.f);
        h1[6] = fmaxf(fmaf(sij, vb.z, sh_b1[6]), 0.f);
        h1[7] = fmaxf(fmaf(sij, vb.w, sh_b1[7]), 0.f);
    }

    // ---------------- layer 2: h2 = relu(h1 @ W2 + b2), staged to LDS ----------------
    #pragma unroll 4
    for (int k = 0; k < 16; ++k) {
        const float4 wa = *(const float4*)(sh_W2t + k * 8);
        const float4 wb = *(const float4*)(sh_W2t + k * 8 + 4);
        float acc = sh_b2[k];
        acc = fmaf(h1[0], wa.x, acc); acc = fmaf(h1[1], wa.y, acc);
        acc = fmaf(h1[2], wa.z, acc); acc = fmaf(h1[3], wa.w, acc);
        acc = fmaf(h1[4], wb.x, acc); acc = fmaf(h1[5], wb.y, acc);
        acc = fmaf(h1[6], wb.z, acc); acc = fmaf(h1[7], wb.w, acc);
        h2w[lane * 17 + k] = fmaxf(acc, 0.f);
    }
    rtw[lane * 5 + 0] = rt0;
    rtw[lane * 5 + 1] = rt1;
    rtw[lane * 5 + 2] = rt2;
    rtw[lane * 5 + 3] = rt3;
    __syncthreads();

    // ---------------- P[h][d] reduction over m; q[d] for free ----------------
    const int hh = lane >> 2, dd = lane & 3;
    float pe = 0.f, q = 0.f;
    #pragma unroll 16
    for (int m = 0; m < 64; ++m) {
        const float hv = h2w[m * 17 + hh];   // 16 distinct addrs -> 16 banks, bcast
        const float rv = rtw[m * 5 + dd];    // 4 distinct addrs, bcast
        pe = fmaf(hv, rv, pe);
        q += rv;
    }
    sh_P[wave][lane] = pe;   // addr == lane: conflict-free
    __syncthreads();

    // ---------------- A[g][d] = sum_h W3[h][g] P[h][d] + b3[g] q[d] ----------------
    {
        const int g0 = hh, g1 = hh + 16;
        float a0 = sh_b3[g0] * q;
        float a1 = sh_b3[g1] * q;
        #pragma unroll 8
        for (int h = 0; h < 16; ++h) {
            const float pv = sh_P[wave][h * 4 + dd];
            a0 = fmaf(sh_W3[h * 32 + g0], pv, a0);
            a1 = fmaf(sh_W3[h * 32 + g1], pv, a1);
        }
        sh_A[wave][lane]      = a0;   // = A[g0][dd] at g0*4+dd == lane
        sh_A[wave][lane + 64] = a1;   // = A[g1][dd]
    }
    __syncthreads();

    // ---------------- D[g][k] = sum_d A[g][d] A[k][d]; coalesced store ----------------
    {
        const int g = lane >> 1, koff = (lane & 1) * 8;
        const float4 Ag = *(const float4*)&sh_A[wave][g * 4];
        float o[8];
        #pragma unroll
        for (int jj = 0; jj < 8; ++jj) {
            const float4 Ak = *(const float4*)&sh_A[wave][(koff + jj) * 4];
            o[jj] = fmaf(Ag.x, Ak.x, fmaf(Ag.y, Ak.y, fmaf(Ag.z, Ak.z, Ag.w * Ak.w)));
        }
        float* op = out + (size_t)atom * 512 + lane * 8;
        *(float4*)(op)     = make_float4(o[0], o[1], o[2], o[3]);
        *(float4*)(op + 4) = make_float4(o[4], o[5], o[6], o[7]);
    }
}

extern "C" void kernel_launch(void* const* d_in, const int* in_sizes, int n_in,
                              void* d_out, int out_size, void* d_ws, size_t ws_size,
                              hipStream_t stream) {
    const float* pos   = (const float*)d_in[0];
    const int*   typ   = (const int*)d_in[1];
    const int*   ngh   = (const int*)d_in[2];
    desc_kernel<<<dim3((SS * NN) / 4), dim3(256), 0, stream>>>(
        pos, typ, ngh,
        (const float*)d_in[3],  (const float*)d_in[4],
        (const float*)d_in[5],  (const float*)d_in[6],
        (const float*)d_in[7],  (const float*)d_in[8],
        (const float*)d_in[9],  (const float*)d_in[10],
        (const float*)d_in[11], (const float*)d_in[12],
        (const float*)d_in[13], (const float*)d_in[14],
        (const float*)d_in[15], (const float*)d_in[16],
        (float*)d_out);
}

// Round 2
// 130.538 us; speedup vs baseline: 1.1633x; 1.1633x over previous
//
#include <hip/hip_runtime.h>
#include <math.h>

#define SS 8
#define NN 4096
#define MM 64
#define LBOX 20.0f

typedef __attribute__((ext_vector_type(8))) short short8;
typedef __attribute__((ext_vector_type(4))) float floatx4;

__device__ inline unsigned short f2bf(float x) {
    unsigned u = __float_as_uint(x);
    u += 0x7fffu + ((u >> 16) & 1u);   // round-to-nearest-even
    return (unsigned short)(u >> 16);
}

// One wave per atom (lane = neighbor). P[16][4] = H^T R via bf16 MFMA on the
// (previously idle) matrix pipe; q via all-ones A-frag MFMA. B cols replicated
// (c&3) so every lane holds valid P rows and q[lane&3] in registers.
// A[32][4] = en3^T P + b3 (x) q ; D[32][16] = A * A[:16]^T  (fp32).
__global__ __launch_bounds__(256) void desc_kernel(
    const float* __restrict__ pos,      // [S*N*3]
    const int*   __restrict__ types,    // [S*N]
    const int*   __restrict__ neigh,    // [S*N*M]
    const float* __restrict__ es1_w, const float* __restrict__ es1_b,
    const float* __restrict__ es2_w, const float* __restrict__ es2_b,
    const float* __restrict__ fs1_w, const float* __restrict__ fs1_b,
    const float* __restrict__ fs2_w, const float* __restrict__ fs2_b,
    const float* __restrict__ en1_w, const float* __restrict__ en1_b,
    const float* __restrict__ en2_w, const float* __restrict__ en2_b,
    const float* __restrict__ en3_w, const float* __restrict__ en3_b,
    float* __restrict__ out)            // [S*N*32*16]
{
    __shared__ alignas(16) unsigned short sh_h2[4][16][72]; // bf16 [wave][h][m], row 144B (16B-aligned)
    __shared__ alignas(16) unsigned short sh_rt[4][4][72];  // bf16 [wave][d][m]
    __shared__ alignas(16) float sh_PT[4][4][20];           // fp32 P^T [wave][d][h]
    __shared__ alignas(16) float sh_W3t[32][20];            // en3_w transposed [g][h]
    __shared__ alignas(16) float sh_A[4][128];              // A[g][d] flat g*4+d
    __shared__ alignas(16) float sh_vt[4][8];               // td[pair] @ en1_w
    __shared__ float sh_b3[32];

    const int tid = threadIdx.x;

    // ---------------- per-block preprocessing ----------------
    if (tid < 4) {  // species-pair table -> vt = td @ en1_w
        const float ti = (float)(tid >> 1), tj = (float)(tid & 1);
        float e[4] = {0.f, 0.f, 0.f, 0.f};
        #pragma unroll
        for (int swp = 0; swp < 2; ++swp) {
            const float a = swp ? tj : ti, b = swp ? ti : tj;
            float h[4];
            #pragma unroll
            for (int k = 0; k < 4; ++k)
                h[k] = fmaxf(a * es1_w[k] + b * es1_w[4 + k] + es1_b[k], 0.f);
            #pragma unroll
            for (int k = 0; k < 4; ++k) {
                float acc = es2_b[k];
                #pragma unroll
                for (int j = 0; j < 4; ++j) acc += h[j] * es2_w[j * 4 + k];
                e[k] += acc;
            }
        }
        float f[4];
        #pragma unroll
        for (int k = 0; k < 4; ++k) {
            float acc = fs1_b[k];
            #pragma unroll
            for (int j = 0; j < 4; ++j) acc += e[j] * fs1_w[j * 4 + k];
            f[k] = fmaxf(acc, 0.f);
        }
        float td[4];
        #pragma unroll
        for (int k = 0; k < 4; ++k) {
            float acc = fs2_b[k];
            #pragma unroll
            for (int j = 0; j < 4; ++j) acc += f[j] * fs2_w[j * 4 + k];
            td[k] = acc;
        }
        #pragma unroll
        for (int o = 0; o < 8; ++o) {
            float acc = 0.f;
            #pragma unroll
            for (int d = 0; d < 4; ++d) acc += td[d] * en1_w[d * 8 + o];
            sh_vt[tid][o] = acc;
        }
    }
    {   // W3 transposed: sh_W3t[g][h] = en3_w[h*32+g]; coalesced global read
        int i = tid;
        sh_W3t[i & 31][i >> 5] = en3_w[i];
        i += 256;
        sh_W3t[i & 31][i >> 5] = en3_w[i];
    }
    if (tid < 32) sh_b3[tid] = en3_b[tid];
    __syncthreads();

    const int wave = tid >> 6;
    const int lane = tid & 63;
    const int atom = blockIdx.x * 4 + wave;      // = s*N + n
    const int sbase = atom & ~(NN - 1);          // s*N

    // ---------------- per-neighbor geometry ----------------
    const float xi = pos[atom * 3 + 0];
    const float yi = pos[atom * 3 + 1];
    const float zi = pos[atom * 3 + 2];
    const int   ti = types[atom];

    const int nb  = neigh[atom * MM + lane];
    const int msk = nb < 0;
    const int j   = msk ? 0 : nb;
    const int gj  = sbase + j;

    float dx = pos[gj * 3 + 0] - xi;
    float dy = pos[gj * 3 + 1] - yi;
    float dz = pos[gj * 3 + 2] - zi;
    dx -= LBOX * rintf(dx * (1.0f / LBOX));
    dy -= LBOX * rintf(dy * (1.0f / LBOX));
    dz -= LBOX * rintf(dz * (1.0f / LBOX));
    const float r2   = fmaf(dx, dx, fmaf(dy, dy, fmaf(dz, dz, 1e-12f)));
    const float rinv = rsqrtf(r2);
    const float r    = r2 * rinv;
    const float u    = (r - 2.0f) * 0.25f;
    float swv = 0.5f * __cosf(3.14159265358979323846f * u) + 0.5f;
    swv = (r < 2.0f) ? 1.0f : ((r < 6.0f) ? swv : 0.0f);
    const float sij   = msk ? 0.0f : swv * rinv;
    const float scale = sij * rinv;

    const int tj = types[gj];
    const int tt = ti * 2 + tj;

    // ---------------- h1 (folded layer 1); weights via s_load ----------------
    float h1[8];
    {
        const float4 va = *(const float4*)(&sh_vt[tt][0]);
        const float4 vb = *(const float4*)(&sh_vt[tt][4]);
        h1[0] = fmaxf(fmaf(sij, va.x, en1_b[0]), 0.f);
        h1[1] = fmaxf(fmaf(sij, va.y, en1_b[1]), 0.f);
        h1[2] = fmaxf(fmaf(sij, va.z, en1_b[2]), 0.f);
        h1[3] = fmaxf(fmaf(sij, va.w, en1_b[3]), 0.f);
        h1[4] = fmaxf(fmaf(sij, vb.x, en1_b[4]), 0.f);
        h1[5] = fmaxf(fmaf(sij, vb.y, en1_b[5]), 0.f);
        h1[6] = fmaxf(fmaf(sij, vb.z, en1_b[6]), 0.f);
        h1[7] = fmaxf(fmaf(sij, vb.w, en1_b[7]), 0.f);
    }

    // ---------------- h2 = relu(h1 @ W2 + b2) -> bf16 LDS, transposed [h][m] ----------------
    #pragma unroll
    for (int k = 0; k < 16; ++k) {
        float acc = en2_b[k];                       // uniform -> s_load
        #pragma unroll
        for (int i = 0; i < 8; ++i) acc = fmaf(h1[i], en2_w[i * 16 + k], acc);
        sh_h2[wave][k][lane] = f2bf(fmaxf(acc, 0.f));
    }
    sh_rt[wave][0][lane] = f2bf(sij);
    sh_rt[wave][1][lane] = f2bf(dx * scale);
    sh_rt[wave][2][lane] = f2bf(dy * scale);
    sh_rt[wave][3][lane] = f2bf(dz * scale);
    __syncthreads();

    // ---------------- P = H^T R and q = 1^T R on the matrix pipe ----------------
    const int col = lane & 15;           // A row h / B col c
    const int q4  = lane >> 4;
    const int m0  = q4 * 8;              // k = q4*8 + j  (per 32-chunk)
    floatx4 cP = {0.f, 0.f, 0.f, 0.f};
    floatx4 cQ = {0.f, 0.f, 0.f, 0.f};
    const short8 ones = (short8)(short)0x3F80;   // bf16 1.0 splat
    #pragma unroll
    for (int ck = 0; ck < 2; ++ck) {
        const short8 af = *(const short8*)&sh_h2[wave][col][ck * 32 + m0];
        const short8 bf = *(const short8*)&sh_rt[wave][col & 3][ck * 32 + m0]; // col-replicated
        cP = __builtin_amdgcn_mfma_f32_16x16x32_bf16(af, bf, cP, 0, 0, 0);
        cQ = __builtin_amdgcn_mfma_f32_16x16x32_bf16(ones, bf, cQ, 0, 0, 0);
    }
    // C layout: row=(lane>>4)*4+reg, col=lane&15 -> lane holds P[q4*4+r][col&3]
    if (col < 4) *(floatx4*)&sh_PT[wave][col][q4 * 4] = cP;
    const float qd = cQ[0];              // q[col&3] == q[lane&3]
    __syncthreads();

    // ---------------- A[g][d] = sum_h W3t[g][h] P[h][d] + b3[g] q[d] ----------------
    {
        const int g0 = lane >> 2, dd = lane & 3, g1 = g0 + 16;
        float a0 = sh_b3[g0] * qd;
        float a1 = sh_b3[g1] * qd;
        #pragma unroll
        for (int c = 0; c < 4; ++c) {
            const floatx4 pv = *(const floatx4*)&sh_PT[wave][dd][c * 4];
            const floatx4 w0 = *(const floatx4*)&sh_W3t[g0][c * 4];
            const floatx4 w1 = *(const floatx4*)&sh_W3t[g1][c * 4];
            a0 = fmaf(pv.x, w0.x, a0); a0 = fmaf(pv.y, w0.y, a0);
            a0 = fmaf(pv.z, w0.z, a0); a0 = fmaf(pv.w, w0.w, a0);
            a1 = fmaf(pv.x, w1.x, a1); a1 = fmaf(pv.y, w1.y, a1);
            a1 = fmaf(pv.z, w1.z, a1); a1 = fmaf(pv.w, w1.w, a1);
        }
        sh_A[wave][lane]      = a0;      // lane == g0*4+dd
        sh_A[wave][lane + 64] = a1;
    }
    __syncthreads();

    // ---------------- D[g][k] = sum_d A[g][d] A[k][d]; coalesced store ----------------
    {
        const int g = lane >> 1, koff = (lane & 1) * 8;
        const float4 Ag = *(const float4*)&sh_A[wave][g * 4];
        float o[8];
        #pragma unroll
        for (int jj = 0; jj < 8; ++jj) {
            const float4 Ak = *(const float4*)&sh_A[wave][(koff + jj) * 4];
            o[jj] = fmaf(Ag.x, Ak.x, fmaf(Ag.y, Ak.y, fmaf(Ag.z, Ak.z, Ag.w * Ak.w)));
        }
        float* op = out + (size_t)atom * 512 + lane * 8;
        *(float4*)(op)     = make_float4(o[0], o[1], o[2], o[3]);
        *(float4*)(op + 4) = make_float4(o[4], o[5], o[6], o[7]);
    }
}

extern "C" void kernel_launch(void* const* d_in, const int* in_sizes, int n_in,
                              void* d_out, int out_size, void* d_ws, size_t ws_size,
                              hipStream_t stream) {
    const float* pos   = (const float*)d_in[0];
    const int*   typ   = (const int*)d_in[1];
    const int*   ngh   = (const int*)d_in[2];
    desc_kernel<<<dim3((SS * NN) / 4), dim3(256), 0, stream>>>(
        pos, typ, ngh,
        (const float*)d_in[3],  (const float*)d_in[4],
        (const float*)d_in[5],  (const float*)d_in[6],
        (const float*)d_in[7],  (const float*)d_in[8],
        (const float*)d_in[9],  (const float*)d_in[10],
        (const float*)d_in[11], (const float*)d_in[12],
        (const float*)d_in[13], (const float*)d_in[14],
        (const float*)d_in[15], (const float*)d_in[16],
        (float*)d_out);
}